// Round 5
// baseline (1566406.836 us; speedup 1.0000x reference)
//
#include <hip/hip_runtime.h>

typedef _Float16 half8 __attribute__((ext_vector_type(8)));
typedef float f32x4 __attribute__((ext_vector_type(4)));

__device__ __forceinline__ float fast_sigmoid(float v) {
  return 1.0f / (1.0f + __expf(-v));
}
__device__ __forceinline__ float fast_tanh(float v) {
  return 2.0f / (1.0f + __expf(-2.0f * v)) - 1.0f;
}

#define AL(p)    __hip_atomic_load((p), __ATOMIC_RELAXED, __HIP_MEMORY_SCOPE_AGENT)
#define AS(p, x) __hip_atomic_store((p), (x), __ATOMIC_RELAXED, __HIP_MEMORY_SCOPE_AGENT)
#define PS(p, x) __hip_atomic_store((p), (x), __ATOMIC_RELAXED, __HIP_MEMORY_SCOPE_WORKGROUP)
// LDS frag-index swizzle (validated in r4): kills 8-way staging bank conflicts.
#define SWZ(i) ((i) ^ (((i) >> 6) & 7))

// L2-scope (same-XCD) fresh loads: bypass L1 via sc0, hit the XCD's L2.
__device__ __forceinline__ unsigned ld_flag_sc0(const unsigned* p) {
  unsigned v;
  asm volatile("global_load_dword %0, %1, off sc0\n\ts_waitcnt vmcnt(0)"
               : "=&v"(v) : "v"(p) : "memory");
  return v;
}
__device__ __forceinline__ void ld_h64_sc0(const void* p, half8& a, half8& b,
                                           half8& c, half8& d) {
  float4 f0, f1, f2, f3;
  asm volatile("global_load_dwordx4 %0, %4, off sc0\n\t"
               "global_load_dwordx4 %1, %4, off offset:16 sc0\n\t"
               "global_load_dwordx4 %2, %4, off offset:32 sc0\n\t"
               "global_load_dwordx4 %3, %4, off offset:48 sc0\n\t"
               "s_waitcnt vmcnt(0)"
               : "=&v"(f0), "=&v"(f1), "=&v"(f2), "=&v"(f3)
               : "v"(p) : "memory");
  __builtin_memcpy(&a, &f0, 16); __builtin_memcpy(&b, &f1, 16);
  __builtin_memcpy(&c, &f2, 16); __builtin_memcpy(&d, &f3, 16);
}

__device__ __forceinline__ void cvt_xp(const float4* p, half8& p0, half8& p1) {
  float4 v0 = p[0], v1 = p[1], v2 = p[2], v3 = p[3];
  p0[0] = (_Float16)v0.x; p0[1] = (_Float16)v0.y;
  p0[2] = (_Float16)v0.z; p0[3] = (_Float16)v0.w;
  p0[4] = (_Float16)v1.x; p0[5] = (_Float16)v1.y;
  p0[6] = (_Float16)v1.z; p0[7] = (_Float16)v1.w;
  p1[0] = (_Float16)v2.x; p1[1] = (_Float16)v2.y;
  p1[2] = (_Float16)v2.z; p1[3] = (_Float16)v2.w;
  p1[4] = (_Float16)v3.x; p1[5] = (_Float16)v3.y;
  p1[6] = (_Float16)v3.z; p1[7] = (_Float16)v3.w;
}

// ---------------------------------------------------------------------------
// prep: build frag-ordered f16 copies of W1, W2 (B-operand frag layout).
// ---------------------------------------------------------------------------
__global__ void __launch_bounds__(256) prep_kernel(
    const float* __restrict__ W1, const float* __restrict__ W2,
    _Float16* __restrict__ W1f, _Float16* __restrict__ W2f)
{
  int idx = blockIdx.x * 256 + threadIdx.x;   // grid 512 -> 0..131071
  int m  = idx >> 16;          // 0 -> W1, 1 -> W2
  int i2 = idx & 65535;
  int s = i2 & 7, lane = (i2 >> 3) & 63, ks = (i2 >> 9) & 7, ct = (i2 >> 12) & 15;
  int col = ct * 16 + (lane & 15);
  int k   = ks * 32 + (lane >> 4) * 8 + s;
  float v = (m == 0) ? W1[k * 256 + col] : W2[k * 256 + col];
  _Float16* dst = (m == 0) ? W1f : W2f;
  dst[i2] = (_Float16)v;
}

// ---------------------------------------------------------------------------
// Recurrence v5: 8 groups (32 rows) x 8 col-WGs (128 gate-cols, K=384).
// Wave (rt,e) owns rows rt*16.., gate tiles ct=2q+e  ->  all 4 gates of a dim
// in ONE lane -> in-register LSTM epilogue (r4-validated). h-part B-frags
// pinned in VGPRs. Exchange through h_all; when the group is PROVEN
// co-located on one XCD (runtime XCC_ID handshake), exchange uses plain
// stores + sc0 loads (XCD-L2, ~200cy hops) instead of agent/MALL (~700cy).
// ---------------------------------------------------------------------------
__global__ void __launch_bounds__(256, 1) lstm_rec_kernel(
    const float* __restrict__ x, const float* __restrict__ Wx,
    const float* __restrict__ Wh, const float* __restrict__ bias,
    _Float16* __restrict__ h_all, unsigned* __restrict__ flags,
    unsigned* __restrict__ xcds)
{
  __shared__ __align__(16) _Float16 Wt[8 * 12 * 64 * 8];   // 96 KB [ct][ks][lane][8]
  __shared__ __align__(16) _Float16 At[2 * 12 * 64 * 8];   // 24 KB [rt][ks][lane][8]
  __shared__ __align__(8)  _Float16 h_s[32][36];           // padded transpose buffer

  const int tid = threadIdx.x;
  const int g  = blockIdx.x & 7;    // group
  const int j  = blockIdx.x >> 3;   // dim-owner 0..7 -> h dims j*32..j*32+31
  const int b0 = g * 32;

  unsigned myxcc;
  asm volatile("s_getreg_b32 %0, hwreg(HW_REG_XCC_ID)" : "=s"(myxcc));
  if (tid == 0) AS(&xcds[g * 8 + j], 0x100u | (myxcc & 0xffu));

  // ---- one-time: weight slice 384 x 128 as f16 B-frags (ct = 2q + (d>=16))
  for (int idx = tid; idx < 384 * 128; idx += 256) {
    int k = idx >> 7, c = idx & 127;          // c = q*32 + d
    int q = c >> 5, d = c & 31;
    int gc = q * 256 + j * 32 + d;
    float v = (k < 128) ? Wx[k * 1024 + gc] : Wh[(k - 128) * 1024 + gc];
    int ct = c >> 4, lcol = c & 15;
    int ks = k >> 5, kg = (k >> 3) & 3, s = k & 7;
    Wt[(((ct * 12 + ks) * 64) + kg * 16 + lcol) * 8 + s] = (_Float16)v;
  }

  const int lane = tid & 63, wid = tid >> 6;
  const int rt = wid & 1, e = wid >> 1;        // wave -> rows rt*16.., dim-half e
  const int prow = rt * 16 + ((lane >> 4) << 2);
  const int pc = lane & 15;
  const int gdim = j * 32 + e * 16 + pc;       // global h-dim this lane owns

  const float bv0 = bias[0 * 256 + gdim], bv1 = bias[1 * 256 + gdim],
              bv2 = bias[2 * 256 + gdim], bv3 = bias[3 * 256 + gdim];

  const int srow = tid >> 3, sseg = tid & 7;   // staging: 32 rows x 8 segs
  const int s_rt = srow >> 4, s_lrow = srow & 15;
  const int xi    = (s_rt * 12 + (sseg >> 1)) * 64 + ((sseg & 1) * 2) * 16 + s_lrow;
  const int hbase = (s_rt * 12 + 4 + sseg) * 64 + s_lrow;

  const float4* xb = (const float4*)x + (size_t)(b0 + srow) * 16384 + sseg * 4;
  half8 XP0, XP1;
  cvt_xp(xb, XP0, XP1);                        // x(0), converted at load

  half8* Ag = (half8*)At;
  const half8* Wp = (const half8*)Wt;

  __syncthreads();   // Wt ready

  // ---- hoist h-part B-frags (4q x ks4..11) into VGPRs, pinned against remat
  half8 Bh[32];
  #pragma unroll
  for (int q = 0; q < 4; ++q)
    #pragma unroll
    for (int ks = 0; ks < 8; ++ks) {
      Bh[q * 8 + ks] = Wp[(2 * q + e) * 768 + (ks + 4) * 64 + lane];
      asm volatile("" : "+v"(Bh[q * 8 + ks]));
    }

  // ---- co-location handshake: fast path iff all 8 group WGs share one XCD
  bool fastp = false;
  {
    const unsigned me = 0x100u | (myxcc & 0xffu);
    int iters = 0;
    while (true) {
      unsigned v = (lane < 8) ? AL(&xcds[g * 8 + lane]) : me;
      if (__ballot((v & 0x100u) != 0) == ~0ull) {
        fastp = (__ballot(v == me) == ~0ull);
        break;
      }
      if (++iters > (1 << 18)) break;          // default to agent path
      __builtin_amdgcn_s_sleep(1);
    }
  }

  // ---- stage x(0), x-part MFMA for t=0, prefetch x(1)
  Ag[SWZ(xi)] = XP0; Ag[SWZ(xi + 16)] = XP1;
  __syncthreads();
  f32x4 ax0 = {0.f, 0.f, 0.f, 0.f}, ax1 = ax0, ax2 = ax0, ax3 = ax0;
  #pragma unroll
  for (int ks = 0; ks < 4; ++ks) {
    half8 av = Ag[SWZ(rt * 768 + ks * 64 + lane)];
    ax0 = __builtin_amdgcn_mfma_f32_16x16x32_f16(av, Wp[(0 + e) * 768 + ks * 64 + lane], ax0, 0, 0, 0);
    ax1 = __builtin_amdgcn_mfma_f32_16x16x32_f16(av, Wp[(2 + e) * 768 + ks * 64 + lane], ax1, 0, 0, 0);
    ax2 = __builtin_amdgcn_mfma_f32_16x16x32_f16(av, Wp[(4 + e) * 768 + ks * 64 + lane], ax2, 0, 0, 0);
    ax3 = __builtin_amdgcn_mfma_f32_16x16x32_f16(av, Wp[(6 + e) * 768 + ks * 64 + lane], ax3, 0, 0, 0);
  }
  cvt_xp(xb + 32, XP0, XP1);                   // x(1)

  float cst[4] = {0.f, 0.f, 0.f, 0.f};         // c-state: 4 VGPRs, persistent

  for (int t = 0; t < 512; ++t) {
    // ---- poll producers (per-wave flags) + stage h(t-1)
    if (t > 0) {
      int iters = 0;
      if (fastp) {
        while (true) {
          unsigned v = (lane < 32) ? ld_flag_sc0(&flags[g * 32 + lane]) : (unsigned)t;
          if (__ballot(v >= (unsigned)t) == ~0ull) break;
          if (++iters > (1 << 15)) break;      // valve: garbage, not hang
        }
        half8 q0, q1, q2, q3;
        ld_h64_sc0((const char*)h_all + (((size_t)(t - 1) * 256 + b0 + srow) * 64 + sseg * 8) * 8,
                   q0, q1, q2, q3);
        Ag[SWZ(hbase)]      = q0; Ag[SWZ(hbase + 16)] = q1;
        Ag[SWZ(hbase + 32)] = q2; Ag[SWZ(hbase + 48)] = q3;
      } else {
        while (true) {
          unsigned v = (lane < 32) ? AL(&flags[g * 32 + lane]) : (unsigned)t;
          if (__ballot(v >= (unsigned)t) == ~0ull) break;
          if (++iters > (1 << 15)) break;
          __builtin_amdgcn_s_sleep(1);
        }
        const unsigned long long* hp = (const unsigned long long*)h_all +
            ((size_t)(t - 1) * 256 + b0 + srow) * 64 + sseg * 8;
        union { unsigned long long u[2]; half8 v; } c0, c1, c2, c3;
        c0.u[0] = AL(hp + 0); c0.u[1] = AL(hp + 1);
        c1.u[0] = AL(hp + 2); c1.u[1] = AL(hp + 3);
        c2.u[0] = AL(hp + 4); c2.u[1] = AL(hp + 5);
        c3.u[0] = AL(hp + 6); c3.u[1] = AL(hp + 7);
        Ag[SWZ(hbase)]      = c0.v; Ag[SWZ(hbase + 16)] = c1.v;
        Ag[SWZ(hbase + 32)] = c2.v; Ag[SWZ(hbase + 48)] = c3.v;
      }
    } else {
      half8 zz = {};
      Ag[SWZ(hbase)]      = zz; Ag[SWZ(hbase + 16)] = zz;
      Ag[SWZ(hbase + 32)] = zz; Ag[SWZ(hbase + 48)] = zz;
    }
    __syncthreads();   // B1: h frags ready

    // ---- h-part MFMA on top of precomputed x-part (B from pinned VGPRs)
    #pragma unroll
    for (int ks = 0; ks < 8; ++ks) {
      half8 av = Ag[SWZ(rt * 768 + (ks + 4) * 64 + lane)];
      ax0 = __builtin_amdgcn_mfma_f32_16x16x32_f16(av, Bh[0 * 8 + ks], ax0, 0, 0, 0);
      ax1 = __builtin_amdgcn_mfma_f32_16x16x32_f16(av, Bh[1 * 8 + ks], ax1, 0, 0, 0);
      ax2 = __builtin_amdgcn_mfma_f32_16x16x32_f16(av, Bh[2 * 8 + ks], ax2, 0, 0, 0);
      ax3 = __builtin_amdgcn_mfma_f32_16x16x32_f16(av, Bh[3 * 8 + ks], ax3, 0, 0, 0);
    }

    // ---- LSTM epilogue fully in registers; h -> h_s (transpose buffer)
    #pragma unroll
    for (int r = 0; r < 4; ++r) {
      float iv = fast_sigmoid(ax0[r] + bv0);
      float fv = fast_sigmoid(ax1[r] + bv1);
      float gv = fast_tanh   (ax2[r] + bv2);
      float ov = fast_sigmoid(ax3[r] + bv3);
      cst[r] = fv * cst[r] + iv * gv;
      h_s[prow + r][e * 16 + pc] = (_Float16)(ov * fast_tanh(cst[r]));
    }

    // ---- stage x(t+1) before the same barrier
    if (t < 511) { Ag[SWZ(xi)] = XP0; Ag[SWZ(xi + 16)] = XP1; }
    __syncthreads();   // B2: h_s + x frags ready

    // ---- coalesced u64 h stores; per-wave drain; per-wave flag
    {
      unsigned long long hv;
      __builtin_memcpy(&hv, &h_s[tid >> 3][(tid & 7) * 4], 8);
      unsigned long long* hp = (unsigned long long*)h_all +
          ((size_t)t * 256 + b0 + (tid >> 3)) * 64 + j * 8 + (tid & 7);
      if (fastp) PS(hp, hv); else AS(hp, hv);
    }
    asm volatile("s_waitcnt vmcnt(0)" ::: "memory");
    if (lane == 0) {
      unsigned* fp = &flags[g * 32 + j * 4 + wid];
      if (fastp) PS(fp, (unsigned)(t + 1)); else AS(fp, (unsigned)(t + 1));
    }

    // ---- tail (overlap window): x-part MFMA for t+1, prefetch x(t+2)
    if (t < 511) {
      ax0 = (f32x4){0.f, 0.f, 0.f, 0.f}; ax1 = ax0; ax2 = ax0; ax3 = ax0;
      #pragma unroll
      for (int ks = 0; ks < 4; ++ks) {
        half8 av = Ag[SWZ(rt * 768 + ks * 64 + lane)];
        ax0 = __builtin_amdgcn_mfma_f32_16x16x32_f16(av, Wp[(0 + e) * 768 + ks * 64 + lane], ax0, 0, 0, 0);
        ax1 = __builtin_amdgcn_mfma_f32_16x16x32_f16(av, Wp[(2 + e) * 768 + ks * 64 + lane], ax1, 0, 0, 0);
        ax2 = __builtin_amdgcn_mfma_f32_16x16x32_f16(av, Wp[(4 + e) * 768 + ks * 64 + lane], ax2, 0, 0, 0);
        ax3 = __builtin_amdgcn_mfma_f32_16x16x32_f16(av, Wp[(6 + e) * 768 + ks * 64 + lane], ax3, 0, 0, 0);
      }
      int tn = (t + 2 < 512) ? (t + 2) : 511;
      cvt_xp(xb + (size_t)tn * 32, XP0, XP1);
    }
  }
}

// ---------------------------------------------------------------------------
// Head: per WG 64 rows of [T*B, H]; fused GEMM1->tanh->GEMM2->tanh->dot(W3).
// ---------------------------------------------------------------------------
__device__ __forceinline__ void head_gemm(const _Float16* __restrict__ A,
                                          const _Float16* __restrict__ Wf,
                                          const float* __restrict__ bvec,
                                          _Float16* __restrict__ Yd,
                                          int lane, int w)
{
  const half8* Af = (const half8*)A + w * 512 + lane;
  for (int ct = 0; ct < 16; ++ct) {
    const half8* Bf = (const half8*)Wf + ct * 512 + lane;
    f32x4 acc = {0.f, 0.f, 0.f, 0.f};
    #pragma unroll
    for (int ks = 0; ks < 8; ++ks)
      acc = __builtin_amdgcn_mfma_f32_16x16x32_f16(Af[ks * 64], Bf[ks * 64], acc, 0, 0, 0);
    int col = ct * 16 + (lane & 15);
    float bb = bvec[col];
    int ks2 = col >> 5, kg2 = (col >> 3) & 3, s2 = col & 7;
    #pragma unroll
    for (int r = 0; r < 4; ++r) {
      int row = w * 16 + ((lane >> 4) << 2) + r;
      float v = fast_tanh(acc[r] + bb);
      Yd[(((w * 8 + ks2) * 64) + kg2 * 16 + (row & 15)) * 8 + s2] = (_Float16)v;
    }
  }
}

__global__ void __launch_bounds__(256) head_kernel(
    const _Float16* __restrict__ h_all,
    const _Float16* __restrict__ W1f, const _Float16* __restrict__ W2f,
    const float* __restrict__ b1, const float* __restrict__ b2,
    const float* __restrict__ W3, const float* __restrict__ b3,
    float* __restrict__ out)
{
  __shared__ __align__(16) _Float16 A_s[16384];   // 32 KB
  __shared__ __align__(16) _Float16 Y_s[16384];   // 32 KB
  const int tid = threadIdx.x;
  const size_t r0 = (size_t)blockIdx.x * 64;

  {
    int row = tid >> 2, seg = tid & 3;
    int rtl = row >> 4, lrow = row & 15;
    const half8* hp = (const half8*)(h_all + (r0 + row) * 256 + seg * 64);
    #pragma unroll
    for (int i = 0; i < 8; ++i) {
      int k0 = seg * 64 + i * 8;
      int ks = k0 >> 5, kg = (k0 >> 3) & 3;
      ((half8*)A_s)[(rtl * 8 + ks) * 64 + kg * 16 + lrow] = hp[i];
    }
  }
  __syncthreads();

  const int lane = tid & 63, w = tid >> 6;
  head_gemm(A_s, W1f, b1, Y_s, lane, w);   // y1 = tanh(h @ W1 + b1)
  __syncthreads();
  head_gemm(Y_s, W2f, b2, A_s, lane, w);   // y2 = tanh(y1 @ W2 + b2)
  __syncthreads();

  {
    int row = tid >> 2, part = tid & 3;
    int rtl = row >> 4, lrow = row & 15;
    float p = 0.f;
    #pragma unroll
    for (int kk = 0; kk < 8; ++kk) {
      int k0 = part * 64 + kk * 8;
      int ks = k0 >> 5, kg = (k0 >> 3) & 3;
      half8 y = ((const half8*)A_s)[(rtl * 8 + ks) * 64 + kg * 16 + lrow];
      #pragma unroll
      for (int i = 0; i < 8; ++i) p += (float)y[i] * W3[k0 + i];
    }
    p += __shfl_xor(p, 1);
    p += __shfl_xor(p, 2);
    if (part == 0) {
      size_t r = r0 + row;                 // r = t*256 + b
      int tt = (int)(r >> 8), bb = (int)(r & 255);
      out[(size_t)bb * 512 + tt] = p + b3[0];
    }
  }
}

// ---------------------------------------------------------------------------
extern "C" void kernel_launch(void* const* d_in, const int* in_sizes, int n_in,
                              void* d_out, int out_size, void* d_ws, size_t ws_size,
                              hipStream_t stream)
{
  const float* x  = (const float*)d_in[0];
  const float* Wx = (const float*)d_in[1];
  const float* Wh = (const float*)d_in[2];
  const float* b  = (const float*)d_in[3];
  const float* W1 = (const float*)d_in[4];
  const float* b1 = (const float*)d_in[5];
  const float* W2 = (const float*)d_in[6];
  const float* b2 = (const float*)d_in[7];
  const float* W3 = (const float*)d_in[8];
  const float* b3 = (const float*)d_in[9];
  float* out = (float*)d_out;

  char* ws = (char*)d_ws;
  unsigned*  flags = (unsigned*)ws;                        // 256 u32 (per-wave)
  unsigned*  xcds  = (unsigned*)(ws + 2048);               // 64 u32 handshake
  _Float16*  W1f   = (_Float16*)(ws + 4096);               // 128 KB
  _Float16*  W2f   = (_Float16*)(ws + 4096 + 131072);      // 128 KB
  _Float16*  h_all = (_Float16*)(ws + 4096 + 262144);      // [512][256][256] f16 = 64 MB
  if (ws_size < (size_t)4096 + 262144 + 67108864) return;  // insufficient scratch

  hipMemsetAsync(ws, 0, 4096, stream);   // clear flags + handshake each replay
  hipLaunchKernelGGL(prep_kernel, dim3(512), dim3(256), 0, stream,
                     W1, W2, W1f, W2f);
  hipLaunchKernelGGL(lstm_rec_kernel, dim3(64), dim3(256), 0, stream,
                     x, Wx, Wh, b, h_all, flags, xcds);
  hipLaunchKernelGGL(head_kernel, dim3(2048), dim3(256), 0, stream,
                     h_all, W1f, W2f, b1, b2, W3, b3, out);
}

// Round 6
// 8805.480 us; speedup vs baseline: 177.8900x; 177.8900x over previous
//
#include <hip/hip_runtime.h>

typedef _Float16 half8 __attribute__((ext_vector_type(8)));
typedef float f32x4 __attribute__((ext_vector_type(4)));

__device__ __forceinline__ float fast_sigmoid(float v) {
  return 1.0f / (1.0f + __expf(-v));
}
__device__ __forceinline__ float fast_tanh(float v) {
  return 2.0f / (1.0f + __expf(-2.0f * v)) - 1.0f;
}

#define AL(p)    __hip_atomic_load((p), __ATOMIC_RELAXED, __HIP_MEMORY_SCOPE_AGENT)
#define AS(p, x) __hip_atomic_store((p), (x), __ATOMIC_RELAXED, __HIP_MEMORY_SCOPE_AGENT)
#define TAGMSK 0xFFFF0000FFFF0000ull

__device__ __forceinline__ half8 cvt2(float4 a, float4 b) {
  half8 o;
  o[0] = (_Float16)a.x; o[1] = (_Float16)a.y; o[2] = (_Float16)a.z; o[3] = (_Float16)a.w;
  o[4] = (_Float16)b.x; o[5] = (_Float16)b.y; o[6] = (_Float16)b.z; o[7] = (_Float16)b.w;
  return o;
}

// ---------------------------------------------------------------------------
// prep: build frag-ordered f16 copies of W1, W2 (B-operand frag layout:
// ((ct*8+ks)*64+lane)*8+s  holds  W[k=ks*32+(lane>>4)*8+s][col=ct*16+(lane&15)])
// ---------------------------------------------------------------------------
__global__ void __launch_bounds__(256) prep_kernel(
    const float* __restrict__ W1, const float* __restrict__ W2,
    _Float16* __restrict__ W1f, _Float16* __restrict__ W2f)
{
  int idx = blockIdx.x * 256 + threadIdx.x;   // grid 512 -> 0..131071
  int m  = idx >> 16;          // 0 -> W1, 1 -> W2
  int i2 = idx & 65535;
  int s = i2 & 7, lane = (i2 >> 3) & 63, ks = (i2 >> 9) & 7, ct = (i2 >> 12) & 15;
  int col = ct * 16 + (lane & 15);
  int k   = ks * 32 + (lane >> 4) * 8 + s;
  float v = (m == 0) ? W1[k * 256 + col] : W2[k * 256 + col];
  _Float16* dst = (m == 0) ? W1f : W2f;
  dst[i2] = (_Float16)v;
}

// ---------------------------------------------------------------------------
// Recurrence v6: barrier-free per-wave engines. 16 WGs (2 row-groups x 8
// dim-WGs); each of the 4 waves owns 32 rows as TWO chains of 16, x its WG's
// 32 h-dims (all 4 gates -> in-register epilogue, c-state in VGPRs).
// Exchange: tagged u32 (tag=t+1 | f16) in ping-pong hx[t&1], agent-scope u64
// atomics (r4-validated). Chains alternate -> prefetched tagged loads are
// ~one phase old at consumption -> first-try tag hits, MALL latency hidden.
// No __syncthreads in the loop; no flags; stale reads caught by tags;
// slot overwrite safety by value dependence (producer of h(t+2) must first
// read h(t+1), which we store only after consuming h(t)).
// ---------------------------------------------------------------------------
#define DO_PHASE(CST, HV, XF, XB4, ROWC, ISSUE_ON, PAR_ISSUE, ROWCO, HVO)      \
  {                                                                            \
    f32x4 ac[2][4];                                                            \
    _Pragma("unroll")                                                          \
    for (int u = 0; u < 2; ++u)                                                \
      _Pragma("unroll")                                                        \
      for (int q = 0; q < 4; ++q) ac[u][q] = (f32x4){0.f, 0.f, 0.f, 0.f};      \
    /* x-part MFMA (ks 0..3) from pre-converted frags */                       \
    _Pragma("unroll")                                                          \
    for (int ks = 0; ks < 4; ++ks)                                             \
      _Pragma("unroll")                                                        \
      for (int u = 0; u < 2; ++u)                                              \
        _Pragma("unroll")                                                      \
        for (int q = 0; q < 4; ++q)                                            \
          ac[u][q] = __builtin_amdgcn_mfma_f32_16x16x32_f16(                   \
              XF[ks], Wp8[(2*q+u)*768 + ks*64 + lane], ac[u][q], 0, 0, 0);     \
    /* reload + convert x(t+1) into XF (consumed next phase of this chain) */  \
    if (t < 511) {                                                             \
      _Pragma("unroll")                                                        \
      for (int ks = 0; ks < 4; ++ks)                                           \
        XF[ks] = cvt2(XB4[(size_t)(t+1)*32 + ks*8],                            \
                      XB4[(size_t)(t+1)*32 + ks*8 + 1]);                       \
    }                                                                          \
    /* tag-check prefetched h(t-1); rare retry loop on stale */                \
    half8 hf[8];                                                               \
    if (t > 0) {                                                               \
      const unsigned long long want =                                          \
          ((unsigned long long)(unsigned)t << 16) |                            \
          ((unsigned long long)(unsigned)t << 48);                             \
      unsigned long long diff = 0;                                             \
      _Pragma("unroll")                                                        \
      for (int i = 0; i < 32; ++i) diff |= (HV[i] & TAGMSK) ^ want;            \
      if (diff != 0) {                                                         \
        const unsigned long long* hp = (const unsigned long long*)hx +         \
            (size_t)(((t - 1) & 1) ? 32768 : 0) +                              \
            (ROWC + (lane & 15)) * 128 + ((lane >> 4) << 2);                   \
        int iters = 0;                                                         \
        do {                                                                   \
          diff = 0;                                                            \
          _Pragma("unroll")                                                    \
          for (int i = 0; i < 32; ++i) {                                       \
            HV[i] = AL(hp + (i >> 2) * 16 + (i & 3));                          \
            diff |= (HV[i] & TAGMSK) ^ want;                                   \
          }                                                                    \
        } while (diff != 0 && ++iters < (1 << 17));                            \
      }                                                                        \
      _Pragma("unroll")                                                        \
      for (int ks = 0; ks < 8; ++ks) {                                         \
        union { unsigned u[4]; half8 v; } pk;                                  \
        _Pragma("unroll")                                                      \
        for (int p = 0; p < 4; ++p) {                                          \
          unsigned long long v = HV[ks * 4 + p];                               \
          pk.u[p] = (unsigned)(v & 0xFFFFu) | ((unsigned)(v >> 32) << 16);     \
        }                                                                      \
        hf[ks] = pk.v;                                                         \
      }                                                                        \
    } else {                                                                   \
      _Pragma("unroll")                                                        \
      for (int ks = 0; ks < 8; ++ks) hf[ks] = (half8){};                       \
    }                                                                          \
    /* h-part MFMA (ks 4..11) */                                               \
    _Pragma("unroll")                                                          \
    for (int ks = 0; ks < 8; ++ks)                                             \
      _Pragma("unroll")                                                        \
      for (int u = 0; u < 2; ++u)                                              \
        _Pragma("unroll")                                                      \
        for (int q = 0; q < 4; ++q)                                            \
          ac[u][q] = __builtin_amdgcn_mfma_f32_16x16x32_f16(                   \
              hf[ks], Wp8[(2*q+u)*768 + (ks+4)*64 + lane], ac[u][q], 0, 0, 0); \
    /* issue the OTHER chain's tagged prefetch (data ~1 phase old) */          \
    if (ISSUE_ON) {                                                            \
      const unsigned long long* hpo = (const unsigned long long*)hx +          \
          (size_t)((PAR_ISSUE) ? 32768 : 0) +                                  \
          (ROWCO + (lane & 15)) * 128 + ((lane >> 4) << 2);                    \
      _Pragma("unroll")                                                        \
      for (int i = 0; i < 32; ++i)                                             \
        HVO[i] = AL(hpo + (i >> 2) * 16 + (i & 3));                            \
      asm volatile("" ::: "memory");   /* pin issue point (no sinking) */      \
    }                                                                          \
    /* in-register LSTM epilogue + tagged h store + f16 h_all store */         \
    _Pragma("unroll")                                                          \
    for (int u = 0; u < 2; ++u) {                                              \
      const int gd = j * 32 + u * 16 + (lane & 15);                            \
      _Pragma("unroll")                                                        \
      for (int r = 0; r < 4; ++r) {                                            \
        float iv = fast_sigmoid(ac[u][0][r] + bv[0 * 2 + u]);                  \
        float fv = fast_sigmoid(ac[u][1][r] + bv[1 * 2 + u]);                  \
        float gv = fast_tanh   (ac[u][2][r] + bv[2 * 2 + u]);                  \
        float ov = fast_sigmoid(ac[u][3][r] + bv[3 * 2 + u]);                  \
        float cv = fv * CST[u * 4 + r] + iv * gv;                              \
        CST[u * 4 + r] = cv;                                                   \
        float hvl = ov * fast_tanh(cv);                                        \
        _Float16 hf16 = (_Float16)hvl;                                         \
        unsigned short hb16; __builtin_memcpy(&hb16, &hf16, 2);                \
        size_t prow = ROWC + ((lane >> 4) << 2) + r;                           \
        AS(hx_st + (size_t)((t & 1) ? 65536 : 0) + prow * 256 + gd,            \
           ((unsigned)(t + 1) << 16) | (unsigned)hb16);                        \
        h_all[((size_t)t * 256 + prow) * 256 + gd] = hf16;                     \
      }                                                                        \
    }                                                                          \
  }

__global__ void __launch_bounds__(256, 1) lstm_rec_kernel(
    const float* __restrict__ x, const float* __restrict__ Wx,
    const float* __restrict__ Wh, const float* __restrict__ bias,
    unsigned* __restrict__ hx_st, _Float16* __restrict__ h_all)
{
  __shared__ __align__(16) _Float16 Wt[8 * 12 * 64 * 8];   // 96 KB [ct][ks][lane][8]
  const unsigned* hx = hx_st;

  const int tid = threadIdx.x;
  const int j  = blockIdx.x & 7;    // dim-WG: h dims j*32 .. j*32+31
  const int gr = blockIdx.x >> 3;   // row-group: rows gr*128 .. gr*128+127

  // ---- one-time: weight slice 384 x 128 as f16 B-frags (ct = 2q + (d>=16))
  for (int idx = tid; idx < 384 * 128; idx += 256) {
    int k = idx >> 7, c = idx & 127;          // c = q*32 + d
    int q = c >> 5, d = c & 31;
    int gc = q * 256 + j * 32 + d;
    float v = (k < 128) ? Wx[k * 1024 + gc] : Wh[(k - 128) * 1024 + gc];
    int ct = c >> 4, lcol = c & 15;
    int ks = k >> 5, kg = (k >> 3) & 3, s = k & 7;
    Wt[(((ct * 12 + ks) * 64) + kg * 16 + lcol) * 8 + s] = (_Float16)v;
  }

  const int lane = tid & 63, wid = tid >> 6;
  const size_t rowcA = (size_t)gr * 128 + wid * 32;   // chain A rows
  const size_t rowcB = rowcA + 16;                    // chain B rows

  float bv[8];                                        // bv[q*2+u]
  #pragma unroll
  for (int q = 0; q < 4; ++q)
    #pragma unroll
    for (int u = 0; u < 2; ++u)
      bv[q * 2 + u] = bias[q * 256 + j * 32 + u * 16 + (lane & 15)];

  const float4* xb4A = (const float4*)x + (rowcA + (lane & 15)) * 16384 + ((lane >> 4) << 1);
  const float4* xb4B = (const float4*)x + (rowcB + (lane & 15)) * 16384 + ((lane >> 4) << 1);

  const half8* Wp8 = (const half8*)Wt;

  __syncthreads();   // Wt ready; the ONLY barrier (loop is barrier-free)

  // ---- per-chain state
  float cstA[8], cstB[8];
  #pragma unroll
  for (int i = 0; i < 8; ++i) { cstA[i] = 0.f; cstB[i] = 0.f; }
  unsigned long long hvA[32], hvB[32];
  #pragma unroll
  for (int i = 0; i < 32; ++i) { hvA[i] = 0ull; hvB[i] = 0ull; }
  half8 XFA[4], XFB[4];
  #pragma unroll
  for (int ks = 0; ks < 4; ++ks) {
    XFA[ks] = cvt2(xb4A[ks * 8], xb4A[ks * 8 + 1]);
    XFB[ks] = cvt2(xb4B[ks * 8], xb4B[ks * 8 + 1]);
  }

  for (int t = 0; t < 512; ++t) {
    // phase A(t): consume hvA (issued last iteration), issue hvB for B(t)
    DO_PHASE(cstA, hvA, XFA, xb4A, rowcA, (t > 0), ((t - 1) & 1), rowcB, hvB)
    // phase B(t): consume hvB, issue hvA for A(t+1)
    DO_PHASE(cstB, hvB, XFB, xb4B, rowcB, (t < 511), (t & 1), rowcA, hvA)
  }
}

// ---------------------------------------------------------------------------
// Head: per WG 64 rows of [T*B, H]; fused GEMM1->tanh->GEMM2->tanh->dot(W3).
// ---------------------------------------------------------------------------
__device__ __forceinline__ void head_gemm(const _Float16* __restrict__ A,
                                          const _Float16* __restrict__ Wf,
                                          const float* __restrict__ bvec,
                                          _Float16* __restrict__ Yd,
                                          int lane, int w)
{
  const half8* Af = (const half8*)A + w * 512 + lane;
  for (int ct = 0; ct < 16; ++ct) {
    const half8* Bf = (const half8*)Wf + ct * 512 + lane;
    f32x4 acc = {0.f, 0.f, 0.f, 0.f};
    #pragma unroll
    for (int ks = 0; ks < 8; ++ks)
      acc = __builtin_amdgcn_mfma_f32_16x16x32_f16(Af[ks * 64], Bf[ks * 64], acc, 0, 0, 0);
    int col = ct * 16 + (lane & 15);
    float bb = bvec[col];
    int ks2 = col >> 5, kg2 = (col >> 3) & 3, s2 = col & 7;
    #pragma unroll
    for (int r = 0; r < 4; ++r) {
      int row = w * 16 + ((lane >> 4) << 2) + r;
      float v = fast_tanh(acc[r] + bb);
      Yd[(((w * 8 + ks2) * 64) + kg2 * 16 + (row & 15)) * 8 + s2] = (_Float16)v;
    }
  }
}

__global__ void __launch_bounds__(256) head_kernel(
    const _Float16* __restrict__ h_all,
    const _Float16* __restrict__ W1f, const _Float16* __restrict__ W2f,
    const float* __restrict__ b1, const float* __restrict__ b2,
    const float* __restrict__ W3, const float* __restrict__ b3,
    float* __restrict__ out)
{
  __shared__ __align__(16) _Float16 A_s[16384];   // 32 KB
  __shared__ __align__(16) _Float16 Y_s[16384];   // 32 KB
  const int tid = threadIdx.x;
  const size_t r0 = (size_t)blockIdx.x * 64;

  {
    int row = tid >> 2, seg = tid & 3;
    int rtl = row >> 4, lrow = row & 15;
    const half8* hp = (const half8*)(h_all + (r0 + row) * 256 + seg * 64);
    #pragma unroll
    for (int i = 0; i < 8; ++i) {
      int k0 = seg * 64 + i * 8;
      int ks = k0 >> 5, kg = (k0 >> 3) & 3;
      ((half8*)A_s)[(rtl * 8 + ks) * 64 + kg * 16 + lrow] = hp[i];
    }
  }
  __syncthreads();

  const int lane = tid & 63, w = tid >> 6;
  head_gemm(A_s, W1f, b1, Y_s, lane, w);   // y1 = tanh(h @ W1 + b1)
  __syncthreads();
  head_gemm(Y_s, W2f, b2, A_s, lane, w);   // y2 = tanh(y1 @ W2 + b2)
  __syncthreads();

  {
    int row = tid >> 2, part = tid & 3;
    int rtl = row >> 4, lrow = row & 15;
    float p = 0.f;
    #pragma unroll
    for (int kk = 0; kk < 8; ++kk) {
      int k0 = part * 64 + kk * 8;
      int ks = k0 >> 5, kg = (k0 >> 3) & 3;
      half8 y = ((const half8*)A_s)[(rtl * 8 + ks) * 64 + kg * 16 + lrow];
      #pragma unroll
      for (int i = 0; i < 8; ++i) p += (float)y[i] * W3[k0 + i];
    }
    p += __shfl_xor(p, 1);
    p += __shfl_xor(p, 2);
    if (part == 0) {
      size_t r = r0 + row;                 // r = t*256 + b
      int tt = (int)(r >> 8), bb = (int)(r & 255);
      out[(size_t)bb * 512 + tt] = p + b3[0];
    }
  }
}

// ---------------------------------------------------------------------------
extern "C" void kernel_launch(void* const* d_in, const int* in_sizes, int n_in,
                              void* d_out, int out_size, void* d_ws, size_t ws_size,
                              hipStream_t stream)
{
  const float* x  = (const float*)d_in[0];
  const float* Wx = (const float*)d_in[1];
  const float* Wh = (const float*)d_in[2];
  const float* b  = (const float*)d_in[3];
  const float* W1 = (const float*)d_in[4];
  const float* b1 = (const float*)d_in[5];
  const float* W2 = (const float*)d_in[6];
  const float* b2 = (const float*)d_in[7];
  const float* W3 = (const float*)d_in[8];
  const float* b3 = (const float*)d_in[9];
  float* out = (float*)d_out;

  char* ws = (char*)d_ws;
  unsigned*  hx    = (unsigned*)ws;                        // ping-pong tagged h: 512 KB
  _Float16*  W1f   = (_Float16*)(ws + 524288);             // 128 KB
  _Float16*  W2f   = (_Float16*)(ws + 655360);             // 128 KB
  _Float16*  h_all = (_Float16*)(ws + 786432);             // [512][256][256] f16 = 64 MB
  if (ws_size < (size_t)786432 + 67108864) return;         // insufficient scratch

  hipMemsetAsync(hx, 0, 524288, stream);   // clear tags every replay
  hipLaunchKernelGGL(prep_kernel, dim3(512), dim3(256), 0, stream,
                     W1, W2, W1f, W2f);
  hipLaunchKernelGGL(lstm_rec_kernel, dim3(16), dim3(256), 0, stream,
                     x, Wx, Wh, b, hx, h_all);
  hipLaunchKernelGGL(head_kernel, dim3(2048), dim3(256), 0, stream,
                     h_all, W1f, W2f, b1, b2, W3, b3, out);
}

// Round 7
// 3066.971 us; speedup vs baseline: 510.7342x; 2.8711x over previous
//
#include <hip/hip_runtime.h>

typedef _Float16 half8 __attribute__((ext_vector_type(8)));
typedef float f32x4 __attribute__((ext_vector_type(4)));

__device__ __forceinline__ float fast_sigmoid(float v) {
  return 1.0f / (1.0f + __expf(-v));
}
__device__ __forceinline__ float fast_tanh(float v) {
  return 2.0f / (1.0f + __expf(-2.0f * v)) - 1.0f;
}

#define AL(p)    __hip_atomic_load((p), __ATOMIC_RELAXED, __HIP_MEMORY_SCOPE_AGENT)
#define AS(p, x) __hip_atomic_store((p), (x), __ATOMIC_RELAXED, __HIP_MEMORY_SCOPE_AGENT)
// LDS frag-index swizzle (r4-validated): spreads staging writes across banks.
#define SWZ(i) ((i) ^ (((i) >> 6) & 7))

__device__ __forceinline__ half8 cvt2(float4 a, float4 b) {
  half8 o;
  o[0] = (_Float16)a.x; o[1] = (_Float16)a.y; o[2] = (_Float16)a.z; o[3] = (_Float16)a.w;
  o[4] = (_Float16)b.x; o[5] = (_Float16)b.y; o[6] = (_Float16)b.z; o[7] = (_Float16)b.w;
  return o;
}

// ---------------------------------------------------------------------------
// prep: frag-ordered f16 copies of W1, W2 (head) and Wx (recurrence x-part).
// B-frag layout: ((ct*KS+ks)*64+lane)*8+s = W[k=ks*32+(lane>>4)*8+s][col=ct*16+(lane&15)]
// ---------------------------------------------------------------------------
__global__ void __launch_bounds__(256) prep_kernel(
    const float* __restrict__ W1, const float* __restrict__ W2,
    const float* __restrict__ Wx,
    _Float16* __restrict__ W1f, _Float16* __restrict__ W2f,
    _Float16* __restrict__ Wxf)
{
  int idx = blockIdx.x * 256 + threadIdx.x;   // grid 1024 -> 0..262143
  if (idx < 131072) {
    int m  = idx >> 16;          // 0 -> W1, 1 -> W2   (256x256 each, 8 ks)
    int i2 = idx & 65535;
    int s = i2 & 7, lane = (i2 >> 3) & 63, ks = (i2 >> 9) & 7, ct = (i2 >> 12) & 15;
    int col = ct * 16 + (lane & 15);
    int k   = ks * 32 + (lane >> 4) * 8 + s;
    float v = (m == 0) ? W1[k * 256 + col] : W2[k * 256 + col];
    _Float16* dst = (m == 0) ? W1f : W2f;
    dst[i2] = (_Float16)v;
  } else {
    int wx = idx - 131072;       // Wx: 128 x 1024 (4 ks, 64 gct)
    int s = wx & 7, lane = (wx >> 3) & 63, ks = (wx >> 9) & 3, gct = wx >> 11;
    int col = gct * 16 + (lane & 15);
    int k   = ks * 32 + (lane >> 4) * 8 + s;
    Wxf[wx] = (_Float16)Wx[k * 1024 + col];
  }
}

// ---------------------------------------------------------------------------
// Recurrence v7: 8 groups (32 rows) x 4 col-WGs. Each WG owns h-dims
// j*64..j*64+63 (all 4 gates; 256 gate-cols; Wh slice 128 KB LDS).
// Wave (rt,e): rows rt*16.., dims e*32..e*32+31; gate tiles ct=q*4+e*2+f
// -> all 4 gates of a dim in ONE lane -> in-register epilogue (r4-validated),
// c-state in VGPRs. x-part: per-wave reg A-frags (prefetched, f16) x Wx
// B-frags hoisted ONCE into 128 VGPRs from frag-ordered GLOBAL copy (cannot
// be rematerialized, unlike LDS) -> tail is reg-only MFMA, no extra barrier.
// Exchange: r3-validated flags + one poll round/step, 4 participants.
// ---------------------------------------------------------------------------
__global__ void __launch_bounds__(256, 1) lstm_rec_kernel(
    const float* __restrict__ x, const float* __restrict__ Wh,
    const float* __restrict__ bias, const _Float16* __restrict__ Wxf,
    _Float16* __restrict__ h_all, unsigned* __restrict__ flags)
{
  __shared__ __align__(16) _Float16 Wt[16 * 8 * 64 * 8];   // 128 KB [ct][ks][lane][8]
  __shared__ __align__(16) _Float16 Ath[2 * 8 * 64 * 8];   // 16 KB h A-frags
  __shared__ __align__(16) _Float16 h_s[32][72];           // 4.5 KB transpose buf

  const int tid = threadIdx.x;
  const int g  = blockIdx.x & 7;    // group: batch rows g*32..g*32+31
  const int j  = blockIdx.x >> 3;   // dim-WG 0..3: h-dims j*64..j*64+63
  const int b0 = g * 32;

  // ---- one-time: Wh slice (256 K x 256 gate-cols) as f16 B-frags in LDS
  for (int idx = tid; idx < 256 * 256; idx += 256) {
    int k = idx >> 8, c = idx & 255;          // c = q*64 + d
    int q = c >> 6, d = c & 63;
    int gc = q * 256 + j * 64 + d;
    int ct = q * 4 + (d >> 4), lcol = d & 15;
    int ks = k >> 5, kg = (k >> 3) & 3, s = k & 7;
    Wt[(((ct * 8 + ks) * 64) + kg * 16 + lcol) * 8 + s] = (_Float16)Wh[k * 1024 + gc];
  }

  const int lane = tid & 63, wid = tid >> 6;
  const int rt = wid & 1, e = wid >> 1;        // wave -> rows rt*16.., dim-half e
  const int pc = lane & 15;
  const int prow = rt * 16 + ((lane >> 4) << 2);
  const int kg2 = (lane >> 4) * 2;

  float bv[4][2];
  #pragma unroll
  for (int q = 0; q < 4; ++q)
    #pragma unroll
    for (int f = 0; f < 2; ++f)
      bv[q][f] = bias[q * 256 + j * 64 + e * 32 + f * 16 + pc];

  const int srow = tid >> 3, sseg = tid & 7;   // staging: 32 rows x 8 segs
  const int s_rt = srow >> 4, s_lrow = srow & 15;
  const int hb = (s_rt * 8 + sseg) * 64 + s_lrow;

  half8* Ath8 = (half8*)Ath;
  const half8* Wp8 = (const half8*)Wt;

  // per-lane x row base (A-frag rows = rt*16 + (lane&15))
  const float4* xl4 = (const float4*)x + (size_t)(b0 + rt * 16 + pc) * 16384;

  __syncthreads();   // Wt ready

  // ---- hoist Wx B-frags ONCE from global frag copy: 4q x 2f x 4ks = 128 VGPRs
  half8 Bx[4][2][4];
  {
    const half8* Wx8 = (const half8*)Wxf;
    #pragma unroll
    for (int q = 0; q < 4; ++q)
      #pragma unroll
      for (int f = 0; f < 2; ++f) {
        int gct = q * 16 + j * 4 + e * 2 + f;
        #pragma unroll
        for (int ks = 0; ks < 4; ++ks)
          Bx[q][f][ks] = Wx8[(gct * 4 + ks) * 64 + lane];
      }
  }

  // ---- pre-loop: XF = x(0) frags; ac = x-part(0); XF <- x(1)
  half8 XF[4];
  #pragma unroll
  for (int ks = 0; ks < 4; ++ks)
    XF[ks] = cvt2(xl4[ks * 8 + kg2], xl4[ks * 8 + kg2 + 1]);
  f32x4 ac[4][2];
  #pragma unroll
  for (int q = 0; q < 4; ++q) {
    ac[q][0] = (f32x4){0.f, 0.f, 0.f, 0.f};
    ac[q][1] = (f32x4){0.f, 0.f, 0.f, 0.f};
  }
  #pragma unroll
  for (int ks = 0; ks < 4; ++ks)
    #pragma unroll
    for (int q = 0; q < 4; ++q) {
      ac[q][0] = __builtin_amdgcn_mfma_f32_16x16x32_f16(XF[ks], Bx[q][0][ks], ac[q][0], 0, 0, 0);
      ac[q][1] = __builtin_amdgcn_mfma_f32_16x16x32_f16(XF[ks], Bx[q][1][ks], ac[q][1], 0, 0, 0);
    }
  #pragma unroll
  for (int ks = 0; ks < 4; ++ks)
    XF[ks] = cvt2(xl4[32 + ks * 8 + kg2], xl4[32 + ks * 8 + kg2 + 1]);

  float cst[8];                                // c-state: f*4+r, persistent
  #pragma unroll
  for (int i = 0; i < 8; ++i) cst[i] = 0.f;

  for (int t = 0; t < 512; ++t) {
    // ---- poll producers (4 flags, one 64B line per group) + stage h(t-1)
    if (t > 0) {
      int iters = 0;
      while (true) {
        unsigned v = (lane < 4) ? AL(&flags[g * 16 + lane]) : (unsigned)t;
        if (__ballot(v >= (unsigned)t) == ~0ull) break;
        if (++iters > (1 << 17)) break;   // valve: garbage instead of hang
        __builtin_amdgcn_s_sleep(1);
      }
      const unsigned long long* hp = (const unsigned long long*)h_all +
          ((size_t)(t - 1) * 256 + b0 + srow) * 64 + sseg * 8;
      union { unsigned long long u[2]; half8 v; } c0, c1, c2, c3;
      c0.u[0] = AL(hp + 0); c0.u[1] = AL(hp + 1);
      c1.u[0] = AL(hp + 2); c1.u[1] = AL(hp + 3);
      c2.u[0] = AL(hp + 4); c2.u[1] = AL(hp + 5);
      c3.u[0] = AL(hp + 6); c3.u[1] = AL(hp + 7);
      Ath8[SWZ(hb)]      = c0.v; Ath8[SWZ(hb + 16)] = c1.v;
      Ath8[SWZ(hb + 32)] = c2.v; Ath8[SWZ(hb + 48)] = c3.v;
    } else {
      half8 zz = {};
      Ath8[SWZ(hb)]      = zz; Ath8[SWZ(hb + 16)] = zz;
      Ath8[SWZ(hb + 32)] = zz; Ath8[SWZ(hb + 48)] = zz;
    }
    __syncthreads();   // B1: h frags ready

    // ---- h-part MFMA on top of precomputed x-part (B from LDS, conflict-free)
    #pragma unroll
    for (int ks = 0; ks < 8; ++ks) {
      half8 av = Ath8[SWZ((rt * 8 + ks) * 64 + lane)];
      #pragma unroll
      for (int q = 0; q < 4; ++q) {
        ac[q][0] = __builtin_amdgcn_mfma_f32_16x16x32_f16(
            av, Wp8[((q * 4 + e * 2 + 0) * 8 + ks) * 64 + lane], ac[q][0], 0, 0, 0);
        ac[q][1] = __builtin_amdgcn_mfma_f32_16x16x32_f16(
            av, Wp8[((q * 4 + e * 2 + 1) * 8 + ks) * 64 + lane], ac[q][1], 0, 0, 0);
      }
    }

    // ---- in-register LSTM epilogue (lane owns i,f,g,o of its dims)
    #pragma unroll
    for (int f = 0; f < 2; ++f)
      #pragma unroll
      for (int r = 0; r < 4; ++r) {
        float iv = fast_sigmoid(ac[0][f][r] + bv[0][f]);
        float fv = fast_sigmoid(ac[1][f][r] + bv[1][f]);
        float gv = fast_tanh   (ac[2][f][r] + bv[2][f]);
        float ov = fast_sigmoid(ac[3][f][r] + bv[3][f]);
        float cv = fv * cst[f * 4 + r] + iv * gv;
        cst[f * 4 + r] = cv;
        h_s[prow + r][e * 32 + f * 16 + pc] = (_Float16)(ov * fast_tanh(cv));
      }
    __syncthreads();   // B2: h_s complete

    // ---- coalesced agent stores of h(t): 16B worth per thread (2 x u64)
    {
      unsigned long long hv0, hv1;
      __builtin_memcpy(&hv0, &h_s[srow][sseg * 8], 8);
      __builtin_memcpy(&hv1, &h_s[srow][sseg * 8 + 4], 8);
      unsigned long long* hp = (unsigned long long*)h_all +
          ((size_t)t * 256 + b0 + srow) * 64 + j * 16 + sseg * 2;
      AS(hp + 0, hv0); AS(hp + 1, hv1);
    }
    __syncthreads();   // B3: all waves' stores drained (vmcnt before barrier)
    if (tid == 0)
      __hip_atomic_store(&flags[g * 16 + j], (unsigned)(t + 1),
                         __ATOMIC_RELEASE, __HIP_MEMORY_SCOPE_AGENT);

    // ---- tail (overlap window, reg-only): x-part for t+1, prefetch x(t+2)
    if (t < 511) {
      #pragma unroll
      for (int q = 0; q < 4; ++q) {
        ac[q][0] = (f32x4){0.f, 0.f, 0.f, 0.f};
        ac[q][1] = (f32x4){0.f, 0.f, 0.f, 0.f};
      }
      #pragma unroll
      for (int ks = 0; ks < 4; ++ks)
        #pragma unroll
        for (int q = 0; q < 4; ++q) {
          ac[q][0] = __builtin_amdgcn_mfma_f32_16x16x32_f16(XF[ks], Bx[q][0][ks], ac[q][0], 0, 0, 0);
          ac[q][1] = __builtin_amdgcn_mfma_f32_16x16x32_f16(XF[ks], Bx[q][1][ks], ac[q][1], 0, 0, 0);
        }
      int tn = (t + 2 < 512) ? (t + 2) : 511;
      #pragma unroll
      for (int ks = 0; ks < 4; ++ks)
        XF[ks] = cvt2(xl4[(size_t)tn * 32 + ks * 8 + kg2],
                      xl4[(size_t)tn * 32 + ks * 8 + kg2 + 1]);
    }
  }
}

// ---------------------------------------------------------------------------
// Head: per WG 64 rows of [T*B, H]; fused GEMM1->tanh->GEMM2->tanh->dot(W3).
// ---------------------------------------------------------------------------
__device__ __forceinline__ void head_gemm(const _Float16* __restrict__ A,
                                          const _Float16* __restrict__ Wf,
                                          const float* __restrict__ bvec,
                                          _Float16* __restrict__ Yd,
                                          int lane, int w)
{
  const half8* Af = (const half8*)A + w * 512 + lane;
  for (int ct = 0; ct < 16; ++ct) {
    const half8* Bf = (const half8*)Wf + ct * 512 + lane;
    f32x4 acc = {0.f, 0.f, 0.f, 0.f};
    #pragma unroll
    for (int ks = 0; ks < 8; ++ks)
      acc = __builtin_amdgcn_mfma_f32_16x16x32_f16(Af[ks * 64], Bf[ks * 64], acc, 0, 0, 0);
    int col = ct * 16 + (lane & 15);
    float bb = bvec[col];
    int ks2 = col >> 5, kg2 = (col >> 3) & 3, s2 = col & 7;
    #pragma unroll
    for (int r = 0; r < 4; ++r) {
      int row = w * 16 + ((lane >> 4) << 2) + r;
      float v = fast_tanh(acc[r] + bb);
      Yd[(((w * 8 + ks2) * 64) + kg2 * 16 + (row & 15)) * 8 + s2] = (_Float16)v;
    }
  }
}

__global__ void __launch_bounds__(256) head_kernel(
    const _Float16* __restrict__ h_all,
    const _Float16* __restrict__ W1f, const _Float16* __restrict__ W2f,
    const float* __restrict__ b1, const float* __restrict__ b2,
    const float* __restrict__ W3, const float* __restrict__ b3,
    float* __restrict__ out)
{
  __shared__ __align__(16) _Float16 A_s[16384];   // 32 KB
  __shared__ __align__(16) _Float16 Y_s[16384];   // 32 KB
  const int tid = threadIdx.x;
  const size_t r0 = (size_t)blockIdx.x * 64;

  {
    int row = tid >> 2, seg = tid & 3;
    int rtl = row >> 4, lrow = row & 15;
    const half8* hp = (const half8*)(h_all + (r0 + row) * 256 + seg * 64);
    #pragma unroll
    for (int i = 0; i < 8; ++i) {
      int k0 = seg * 64 + i * 8;
      int ks = k0 >> 5, kg = (k0 >> 3) & 3;
      ((half8*)A_s)[(rtl * 8 + ks) * 64 + kg * 16 + lrow] = hp[i];
    }
  }
  __syncthreads();

  const int lane = tid & 63, w = tid >> 6;
  head_gemm(A_s, W1f, b1, Y_s, lane, w);   // y1 = tanh(h @ W1 + b1)
  __syncthreads();
  head_gemm(Y_s, W2f, b2, A_s, lane, w);   // y2 = tanh(y1 @ W2 + b2)
  __syncthreads();

  {
    int row = tid >> 2, part = tid & 3;
    int rtl = row >> 4, lrow = row & 15;
    float p = 0.f;
    #pragma unroll
    for (int kk = 0; kk < 8; ++kk) {
      int k0 = part * 64 + kk * 8;
      int ks = k0 >> 5, kg = (k0 >> 3) & 3;
      half8 y = ((const half8*)A_s)[(rtl * 8 + ks) * 64 + kg * 16 + lrow];
      #pragma unroll
      for (int i = 0; i < 8; ++i) p += (float)y[i] * W3[k0 + i];
    }
    p += __shfl_xor(p, 1);
    p += __shfl_xor(p, 2);
    if (part == 0) {
      size_t r = r0 + row;                 // r = t*256 + b
      int tt = (int)(r >> 8), bb = (int)(r & 255);
      out[(size_t)bb * 512 + tt] = p + b3[0];
    }
  }
}

// ---------------------------------------------------------------------------
extern "C" void kernel_launch(void* const* d_in, const int* in_sizes, int n_in,
                              void* d_out, int out_size, void* d_ws, size_t ws_size,
                              hipStream_t stream)
{
  const float* x  = (const float*)d_in[0];
  const float* Wx = (const float*)d_in[1];
  const float* Wh = (const float*)d_in[2];
  const float* b  = (const float*)d_in[3];
  const float* W1 = (const float*)d_in[4];
  const float* b1 = (const float*)d_in[5];
  const float* W2 = (const float*)d_in[6];
  const float* b2 = (const float*)d_in[7];
  const float* W3 = (const float*)d_in[8];
  const float* b3 = (const float*)d_in[9];
  float* out = (float*)d_out;

  char* ws = (char*)d_ws;
  unsigned*  flags = (unsigned*)ws;                        // 128 u32 used (4 KB pad)
  _Float16*  W1f   = (_Float16*)(ws + 4096);               // 128 KB
  _Float16*  W2f   = (_Float16*)(ws + 4096 + 131072);      // 128 KB
  _Float16*  Wxf   = (_Float16*)(ws + 4096 + 262144);      // 256 KB frag-ordered Wx
  _Float16*  h_all = (_Float16*)(ws + 4096 + 524288);      // [512][256][256] f16 = 64 MB
  if (ws_size < (size_t)4096 + 524288 + 67108864) return;  // insufficient scratch

  hipMemsetAsync(flags, 0, 4096, stream);   // clear flags each replay
  hipLaunchKernelGGL(prep_kernel, dim3(1024), dim3(256), 0, stream,
                     W1, W2, Wx, W1f, W2f, Wxf);
  hipLaunchKernelGGL(lstm_rec_kernel, dim3(32), dim3(256), 0, stream,
                     x, Wh, b, Wxf, h_all, flags);
  hipLaunchKernelGGL(head_kernel, dim3(2048), dim3(256), 0, stream,
                     h_all, W1f, W2f, b1, b2, W3, b3, out);
}